// Round 1
// baseline (260.806 us; speedup 1.0000x reference)
//
#include <hip/hip_runtime.h>
#include <hip/hip_bf16.h>

// Problem constants (ODST forward):
//   x                        [B=1024, I=256]        f32
//   feature_selection_logits [I=256, N=512, D=6]    f32
//   feature_thresholds       [N=512, D=6]           f32
//   log_temperatures         [N=512, D=6]           f32
//   response                 [N=512, U=16, C=64]    f32
//   out                      [B=1024, U=16]         f32
#define B_SZ 1024
#define I_SZ 256
#define N_SZ 512
#define D_SZ 6
#define U_SZ 16
#define C_SZ 64
#define K_SZ (N_SZ * D_SZ)   // 3072

// ---------------------------------------------------------------------------
// Kernel 1: sparsemax over last axis (D=6) of feature_selection_logits.
// One thread per (i,n) pair. Sorting network (odd-even, 6 rounds) keeps it
// branchless.
// ---------------------------------------------------------------------------
__global__ __launch_bounds__(256) void sparsemax_k(
    const float* __restrict__ fsl, float* __restrict__ sel) {
  const int t = blockIdx.x * 256 + threadIdx.x;   // 0 .. I*N-1
  const float* z = fsl + (size_t)t * D_SZ;
  float v[D_SZ], s[D_SZ];
#pragma unroll
  for (int d = 0; d < D_SZ; ++d) { v[d] = z[d]; s[d] = v[d]; }

  // odd-even transposition sort, descending, 6 rounds
#define CSWAP(a, b) { float hi = fmaxf(s[a], s[b]); float lo = fminf(s[a], s[b]); s[a] = hi; s[b] = lo; }
#pragma unroll
  for (int r = 0; r < 3; ++r) {
    CSWAP(0, 1) CSWAP(2, 3) CSWAP(4, 5)
    CSWAP(1, 2) CSWAP(3, 4)
  }
#undef CSWAP

  float cs[D_SZ];
  cs[0] = s[0];
#pragma unroll
  for (int j = 1; j < D_SZ; ++j) cs[j] = cs[j - 1] + s[j];
  int kz = 0;
#pragma unroll
  for (int j = 0; j < D_SZ; ++j)
    kz += (1.0f + (float)(j + 1) * s[j] > cs[j]) ? 1 : 0;
  const float tau = (cs[kz - 1] - 1.0f) / (float)kz;

  float* o = sel + (size_t)t * D_SZ;
#pragma unroll
  for (int d = 0; d < D_SZ; ++d) o[d] = fmaxf(v[d] - tau, 0.0f);
}

// ---------------------------------------------------------------------------
// Kernel 2: fv = x @ sel  (M=1024, K=256, N'=3072), fp32 vector GEMM.
// 64x64 tile per block, 4x4 micro-tile per thread, K chunks of 16 via LDS.
// Output stored TRANSPOSED: fvT[k * 1024 + b] so kernel 3 lanes (consecutive
// b) get coalesced loads.
// ---------------------------------------------------------------------------
__global__ __launch_bounds__(256) void gemm_fv(
    const float* __restrict__ x,     // [1024, 256]
    const float* __restrict__ sel,   // [256, 3072]
    float* __restrict__ fvT) {       // [3072, 1024]
  __shared__ float As[16][64];   // [kk][b]  (x tile, transposed in LDS)
  __shared__ float Bs[16][64];   // [kk][k]

  const int t  = threadIdx.x;
  const int tx = t & 15;         // k quad index
  const int ty = t >> 4;         // b quad index
  const int k0 = blockIdx.x * 64;  // gridDim.x = 48
  const int b0 = blockIdx.y * 64;  // gridDim.y = 16

  const int a_row = t >> 2;        // 0..63
  const int a_col = (t & 3) * 4;   // 0,4,8,12
  const int b_row = t >> 4;        // 0..15
  const int b_col = (t & 15) * 4;  // 0..60

  float acc[4][4];
#pragma unroll
  for (int i = 0; i < 4; ++i)
#pragma unroll
    for (int j = 0; j < 4; ++j) acc[i][j] = 0.0f;

  for (int kk = 0; kk < I_SZ; kk += 16) {
    const float4 av = *(const float4*)(x + (size_t)(b0 + a_row) * I_SZ + kk + a_col);
    const float4 bv = *(const float4*)(sel + (size_t)(kk + b_row) * K_SZ + k0 + b_col);
    __syncthreads();  // previous iteration's LDS reads complete
    As[a_col + 0][a_row] = av.x;
    As[a_col + 1][a_row] = av.y;
    As[a_col + 2][a_row] = av.z;
    As[a_col + 3][a_row] = av.w;
    *(float4*)&Bs[b_row][b_col] = bv;
    __syncthreads();
#pragma unroll
    for (int kq = 0; kq < 16; ++kq) {
      const float4 a  = *(const float4*)&As[kq][ty * 4];
      const float4 bb = *(const float4*)&Bs[kq][tx * 4];
      const float af[4] = {a.x, a.y, a.z, a.w};
      const float bf[4] = {bb.x, bb.y, bb.z, bb.w};
#pragma unroll
      for (int i = 0; i < 4; ++i)
#pragma unroll
        for (int j = 0; j < 4; ++j) acc[i][j] += af[i] * bf[j];
    }
  }

  // store transposed: fvT[k][b], 4 consecutive b per float4
#pragma unroll
  for (int j = 0; j < 4; ++j) {
    float4 outv = make_float4(acc[0][j], acc[1][j], acc[2][j], acc[3][j]);
    *(float4*)(fvT + (size_t)(k0 + tx * 4 + j) * B_SZ + b0 + ty * 4) = outv;
  }
}

// ---------------------------------------------------------------------------
// Kernel 3: fused bins -> leaf weights -> response dot -> sum over n.
// Block = 256 threads = 4 waves. Lanes = 64 consecutive b (coalesced fvT
// loads). n is wave-uniform (readfirstlane) so thresholds / response rows
// become scalar (broadcast) loads. Grid = 16 b-tiles x 16 n-splits; each
// wave handles 8 n values; partial sums accumulated via float atomics.
// ---------------------------------------------------------------------------
__global__ __launch_bounds__(256) void tree_k(
    const float* __restrict__ fvT,   // [3072, 1024]
    const float* __restrict__ th,    // [512, 6]
    const float* __restrict__ lt,    // [512, 6]
    const float* __restrict__ resp,  // [512, 16, 64]
    float* __restrict__ out) {       // [1024, 16]
  const int lane   = threadIdx.x & 63;
  const int wave   = threadIdx.x >> 6;   // 0..3
  const int btile  = blockIdx.x & 15;    // 16 b tiles
  const int nsplit = blockIdx.x >> 4;    // 16 n splits
  const int b = btile * 64 + lane;

  float acc[U_SZ];
#pragma unroll
  for (int u = 0; u < U_SZ; ++u) acc[u] = 0.0f;

#pragma unroll 1
  for (int j = 0; j < 8; ++j) {
    const int n = __builtin_amdgcn_readfirstlane(nsplit * 32 + wave * 8 + j);

    float bins0[D_SZ], bins1[D_SZ];
#pragma unroll
    for (int d = 0; d < D_SZ; ++d) {
      const float fv  = fvT[(size_t)(n * D_SZ + d) * B_SZ + b];
      const float tlv = (fv - th[n * D_SZ + d]) * __expf(-lt[n * D_SZ + d]);
      bins1[d] = fminf(fmaxf( 0.5f * tlv + 0.5f, 0.0f), 1.0f);  // +tl bin
      bins0[d] = fminf(fmaxf(-0.5f * tlv + 0.5f, 0.0f), 1.0f);  // -tl bin
    }

    // leaf weights: w[c] = prod_d (bit_d(c) ? bins0[d] : bins1[d])
    float w[C_SZ];
    w[0] = 1.0f;
#pragma unroll
    for (int d = 0; d < D_SZ; ++d) {
      const int len = 1 << d;
#pragma unroll
      for (int q = len - 1; q >= 0; --q) {
        w[q + len] = w[q] * bins0[d];
        w[q]       = w[q] * bins1[d];
      }
    }

    // out[b, u] += sum_c w[c] * resp[n, u, c]
    const float* r = resp + (size_t)n * (U_SZ * C_SZ);
#pragma unroll
    for (int u = 0; u < U_SZ; ++u) {
      float s = 0.0f;
#pragma unroll
      for (int c = 0; c < C_SZ; ++c) s += w[c] * r[u * C_SZ + c];
      acc[u] += s;
    }
  }

#pragma unroll
  for (int u = 0; u < U_SZ; ++u)
    atomicAdd(&out[(size_t)b * U_SZ + u], acc[u]);
}

// ---------------------------------------------------------------------------
extern "C" void kernel_launch(void* const* d_in, const int* in_sizes, int n_in,
                              void* d_out, int out_size, void* d_ws, size_t ws_size,
                              hipStream_t stream) {
  const float* x    = (const float*)d_in[0];
  const float* fsl  = (const float*)d_in[1];
  const float* th   = (const float*)d_in[2];
  const float* lt   = (const float*)d_in[3];
  const float* resp = (const float*)d_in[4];
  float* out = (float*)d_out;

  float* sel = (float*)d_ws;                       // [256*3072]  (3 MB)
  float* fvT = sel + (size_t)I_SZ * K_SZ;          // [3072*1024] (12 MB)

  // 1) sparsemax: 131072 (i,n) pairs
  sparsemax_k<<<(I_SZ * N_SZ) / 256, 256, 0, stream>>>(fsl, sel);

  // 2) feature-value GEMM (stores transposed)
  dim3 g2(K_SZ / 64, B_SZ / 64);  // 48 x 16
  gemm_fv<<<g2, 256, 0, stream>>>(x, sel, fvT);

  // 3) zero out, then fused tree evaluation with atomic accumulation
  hipMemsetAsync(d_out, 0, (size_t)out_size * sizeof(float), stream);
  tree_k<<<256, 256, 0, stream>>>(fvT, th, lt, resp, out);
}